// Round 11
// baseline (2751.871 us; speedup 1.0000x reference)
//
#include <hip/hip_runtime.h>
#include <hip/hip_bf16.h>
#include <stdint.h>

#define NN 100000
#define EE 600000
#define FF 64
#define EDIM 16
#define HH 128
#define LLAYERS 4
#define OO 32

#define SCH 512                         // scan chunk per block
#define SNB ((NN + SCH - 1) / SCH)      // 196 scan blocks

// ---------------------------------------------------------------------------
// ws layout (floats):
//  h   : [0, N*H)            node state
//  PQ  : [N*H, N*3H)         P = h@W1a (cols 0..127), Q = h@W1b (cols 128..255)
//  S   : [N*3H, N*4H)        per-dst hidden sums (raw; k_tagg is fused away)
//  cnt : [N*4H, +N)          in-degree (float)
//  sco : +N ; pmax: +256 ; aux: +130
//  ints: flag(2), rowoff(N+1), cursor(N), src_perm(E), eid_perm(E), bsum(SNB)
//  V   : [L][128][128]       V = W2 @ U_b   (k_prep, once per call)
//  wv  : [L][128]            w = b2 @ U_b
//
// Fusion: update pre-act = h@U_a + inv*(S@V) + inv*cnt*w + ub  (associativity
// of (S@W2)@U_b = S@(W2@U_b)) — removes k_tagg's GEMM + 102MB T round trip.
// ---------------------------------------------------------------------------

// ===== detect edge_index dtype (int64 has all-zero high words)
__global__ __launch_bounds__(64) void k_detect(const unsigned int* __restrict__ w,
                                               int* __restrict__ flag)
{
  const int t = threadIdx.x;
  int z = (w[2*t + 1] == 0u) ? 1 : 0;
  #pragma unroll
  for (int o = 32; o > 0; o >>= 1) z &= __shfl_xor(z, o, 64);
  if (t == 0) *flag = z;
}

// ===== in-degree
__global__ __launch_bounds__(256) void k_cnt(const void* __restrict__ buf,
                                             const int* __restrict__ flag,
                                             float* __restrict__ cnt)
{
  const int is64 = *flag;
  const long long* b64 = (const long long*)buf;
  const int*       b32 = (const int*)buf;
  for (int e = blockIdx.x*256 + threadIdx.x; e < EE; e += gridDim.x*256) {
    const int d = is64 ? (int)b64[EE + e] : b32[EE + e];
    atomicAdd(&cnt[d], 1.0f);
  }
}

// ===== scan pass A: per-block degree sums (coalesced)
__global__ __launch_bounds__(256) void k_scan_a(const float* __restrict__ cnt,
                                                int* __restrict__ bsum)
{
  __shared__ int red[4];
  const int base = blockIdx.x * SCH;
  const int t = threadIdx.x;
  int s = 0;
  const int i0 = base + t, i1 = base + 256 + t;
  if (i0 < NN) s += (int)cnt[i0];
  if (i1 < NN) s += (int)cnt[i1];
  #pragma unroll
  for (int o = 32; o > 0; o >>= 1) s += __shfl_xor(s, o, 64);
  if ((t & 63) == 0) red[t >> 6] = s;
  __syncthreads();
  if (t == 0) bsum[blockIdx.x] = red[0] + red[1] + red[2] + red[3];
}

// ===== scan pass B: exclusive scan of SNB block sums (1 block)
__global__ __launch_bounds__(256) void k_scan_b(int* __restrict__ bsum)
{
  __shared__ int ps[256];
  const int t = threadIdx.x;
  const int v = (t < SNB) ? bsum[t] : 0;
  ps[t] = v;
  __syncthreads();
  for (int off = 1; off < 256; off <<= 1) {
    int u = (t >= off) ? ps[t - off] : 0;
    __syncthreads();
    ps[t] += u;
    __syncthreads();
  }
  if (t < SNB) bsum[t] = ps[t] - v;   // exclusive block offsets
}

// ===== scan pass C: local exclusive scan + block offset -> rowoff, cursor
__global__ __launch_bounds__(256) void k_scan_c(const float* __restrict__ cnt,
                                                const int* __restrict__ bsum,
                                                int* __restrict__ rowoff,
                                                int* __restrict__ cursor)
{
  __shared__ int vals[SCH];
  __shared__ int ps[256];
  const int base = blockIdx.x * SCH;
  const int t = threadIdx.x;
  const int i0 = base + t, i1 = base + 256 + t;
  vals[t]       = (i0 < NN) ? (int)cnt[i0] : 0;
  vals[256 + t] = (i1 < NN) ? (int)cnt[i1] : 0;
  __syncthreads();
  const int a = vals[2*t], b = vals[2*t + 1];
  const int pair = a + b;
  ps[t] = pair;
  __syncthreads();
  for (int off = 1; off < 256; off <<= 1) {
    int u = (t >= off) ? ps[t - off] : 0;
    __syncthreads();
    ps[t] += u;
    __syncthreads();
  }
  const int excl = bsum[blockIdx.x] + ps[t] - pair;
  const int j0 = base + 2*t, j1 = j0 + 1;
  if (j0 < NN) { rowoff[j0] = excl;     cursor[j0] = excl; }
  if (j1 < NN) { rowoff[j1] = excl + a; cursor[j1] = excl + a; }
  if (j1 == NN - 1) rowoff[NN] = excl + pair;   // NN even -> last elem is a j1
}

// ===== bucket edges by dst
__global__ __launch_bounds__(256) void k_scatter(const void* __restrict__ buf,
                                                 const int* __restrict__ flag,
                                                 int* __restrict__ cursor,
                                                 int* __restrict__ src_perm,
                                                 int* __restrict__ eid_perm)
{
  const int is64 = *flag;
  const long long* b64 = (const long long*)buf;
  const int*       b32 = (const int*)buf;
  for (int e = blockIdx.x*256 + threadIdx.x; e < EE; e += gridDim.x*256) {
    const int s = is64 ? (int)b64[e]      : b32[e];
    const int d = is64 ? (int)b64[EE + e] : b32[EE + e];
    const int pos = atomicAdd(&cursor[d], 1);
    src_perm[pos] = s;
    eid_perm[pos] = e;
  }
}

// ===== prep: V[i] = W2[i] @ Ub[i], wv[i] = b2[i] @ Ub[i]  (Ub = U rows 128..255)
// grid = LLAYERS*8; block handles 16 rows of V for one layer.
__global__ __launch_bounds__(256) void k_prep(
    const float* __restrict__ mw2, const float* __restrict__ mb2,
    const float* __restrict__ uw, float* __restrict__ V,
    float* __restrict__ wv)
{
  __shared__ float w2s[16*128];
  const int L = blockIdx.x >> 3, sub = blockIdx.x & 7;
  const int t = threadIdx.x, col = t & 127, half = t >> 7;
  const float* W2 = mw2 + (size_t)L*128*128;
  const float* Ub = uw  + (size_t)L*256*128 + 128*128;
  const float* b2 = mb2 + (size_t)L*128;
  float* Vl = V  + (size_t)L*128*128;
  float* wl = wv + (size_t)L*128;
  // stage W2 rows [sub*16, sub*16+16) : 512 float4
  const float4* W24 = (const float4*)W2;
  ((float4*)w2s)[t]       = W24[sub*512 + t];
  ((float4*)w2s)[256 + t] = W24[sub*512 + 256 + t];
  // column col of Ub in registers
  float ur[128];
  #pragma unroll 8
  for (int k = 0; k < 128; ++k) ur[k] = Ub[k*128 + col];
  __syncthreads();
  #pragma unroll
  for (int i = 0; i < 8; ++i) {
    const int r = half*8 + i;
    float acc = 0.f;
    #pragma unroll 8
    for (int k = 0; k < 128; ++k) acc = fmaf(w2s[r*128 + k], ur[k], acc);
    Vl[(size_t)(sub*16 + r)*128 + col] = acc;
  }
  if (sub == 0 && half == 0) {
    float acc = 0.f;
    #pragma unroll 8
    for (int k = 0; k < 128; ++k) acc = fmaf(b2[k], ur[k], acc);
    wl[col] = acc;
  }
}

// ===== encoder: h = relu(LN(relu(x@w1+b1))@w2+b2), fused, 2 nodes/block-iter
__global__ __launch_bounds__(256) void k_enc(
    const float* __restrict__ nf, const float* __restrict__ w1,
    const float* __restrict__ b1, const float* __restrict__ lng,
    const float* __restrict__ lnb, const float* __restrict__ w2,
    const float* __restrict__ b2, float* __restrict__ h)
{
  __shared__ float lds[4096];
  __shared__ float red[8];
  const int t = threadIdx.x;
  const int col = t & 127, g = t >> 7;
  float br1[64], br2[128];
  const float4* w14 = (const float4*)w1;
  #pragma unroll
  for (int c = 0; c < 2; ++c) {
    #pragma unroll
    for (int v = 0; v < 4; ++v) ((float4*)lds)[t + v*256] = w14[c*1024 + t + v*256];
    __syncthreads();
    #pragma unroll
    for (int k = 0; k < 32; ++k) br1[c*32+k] = lds[k*128 + col];
    __syncthreads();
  }
  const float4* w24 = (const float4*)w2;
  #pragma unroll
  for (int c = 0; c < 4; ++c) {
    #pragma unroll
    for (int v = 0; v < 4; ++v) ((float4*)lds)[t + v*256] = w24[c*1024 + t + v*256];
    __syncthreads();
    #pragma unroll
    for (int k = 0; k < 32; ++k) br2[c*32+k] = lds[k*128 + col];
    __syncthreads();
  }
  const float b1c = b1[col], gc = lng[col], bc = lnb[col], b2c = b2[col];
  float* xs = lds;          // xs[2][64]
  float* ys = lds + 128;    // ys[2][128]
  for (int n0 = blockIdx.x * 2; n0 < NN; n0 += gridDim.x * 2) {
    const int node = n0 + g;
    if (col < 16) ((float4*)xs)[g*16 + col] = ((const float4*)nf)[(size_t)node*16 + col];
    __syncthreads();
    float a = b1c;
    #pragma unroll
    for (int k = 0; k < 64; ++k) a = fmaf(xs[g*64+k], br1[k], a);
    float v = fmaxf(a, 0.f);
    float s1 = v, s2 = v*v;
    #pragma unroll
    for (int o = 32; o > 0; o >>= 1) { s1 += __shfl_xor(s1, o, 64); s2 += __shfl_xor(s2, o, 64); }
    const int w = (t >> 6) & 1;
    if ((t & 63) == 0) { red[(g*2+w)*2] = s1; red[(g*2+w)*2+1] = s2; }
    __syncthreads();
    const float sum1 = red[g*4] + red[g*4+2], sum2 = red[g*4+1] + red[g*4+3];
    const float mu = sum1 * (1.f/128.f);
    const float var = sum2 * (1.f/128.f) - mu*mu;
    const float y = (v - mu) * rsqrtf(var + 1e-5f) * gc + bc;
    ys[g*128+col] = y;
    __syncthreads();
    float a2 = b2c;
    #pragma unroll
    for (int k = 0; k < 128; ++k) a2 = fmaf(ys[g*128+k], br2[k], a2);
    h[(size_t)node*128 + col] = fmaxf(a2, 0.f);
    __syncthreads();
  }
}

// ===== PQ = h @ [W1a | W1b]  (N x 256), 4 nodes/block-iter
__global__ __launch_bounds__(256) void k_pq(
    const float* __restrict__ h, const float* __restrict__ W1,
    float* __restrict__ PQ)
{
  __shared__ float lds[4096];
  const int t = threadIdx.x;
  const int col = t & 127, hb = t >> 7;
  float br[128];
  const float4* B4 = (const float4*)W1;
  #pragma unroll
  for (int c = 0; c < 8; ++c) {
    #pragma unroll
    for (int v = 0; v < 4; ++v) ((float4*)lds)[t + v*256] = B4[c*1024 + t + v*256];
    __syncthreads();
    if ((c >> 2) == hb) {
      #pragma unroll
      for (int k = 0; k < 32; ++k) br[(c&3)*32 + k] = lds[k*128 + col];
    }
    __syncthreads();
  }
  float4* hs4 = (float4*)lds;
  for (int n0 = blockIdx.x*4; n0 < NN; n0 += gridDim.x*4) {
    if (t < 128) hs4[t] = ((const float4*)h)[(size_t)n0*32 + t];
    __syncthreads();
    float ac[4] = {0.f,0.f,0.f,0.f};
    #pragma unroll
    for (int kq = 0; kq < 32; ++kq) {
      const float b0 = br[4*kq], b1_ = br[4*kq+1], b2_ = br[4*kq+2], b3_ = br[4*kq+3];
      #pragma unroll
      for (int j = 0; j < 4; ++j) {
        float4 a = hs4[j*32 + kq];
        ac[j] = fmaf(a.x,b0, fmaf(a.y,b1_, fmaf(a.z,b2_, fmaf(a.w,b3_, ac[j]))));
      }
    }
    #pragma unroll
    for (int j = 0; j < 4; ++j) PQ[(size_t)(n0+j)*256 + t] = ac[j];
    __syncthreads();
  }
}

// ===== edge (CSR): per dst node, acc += relu(P[src]+Q[dst]+ef@W1c+b1); S once
__global__ __launch_bounds__(256) void k_edge_csr(
    const int* __restrict__ rowoff, const int* __restrict__ src_perm,
    const int* __restrict__ eid_perm, const float* __restrict__ ef,
    const float* __restrict__ PQ, const float* __restrict__ W1c,
    const float* __restrict__ b1, float* __restrict__ S)
{
  const int t = threadIdx.x;
  const int lane = t & 63, wid = t >> 6;
  float wr0[16], wr1[16];
  #pragma unroll
  for (int k = 0; k < 16; ++k) {
    wr0[k] = W1c[k*128 + lane];
    wr1[k] = W1c[k*128 + 64 + lane];
  }
  const float b1c0 = b1[lane], b1c1 = b1[64+lane];
  const int nwaves = gridDim.x * 4;
  for (int n = blockIdx.x*4 + wid; n < NN; n += nwaves) {
    const int jb = rowoff[n], je = rowoff[n+1];
    const float* Qp = PQ + (size_t)n*256 + 128;
    const float q0 = Qp[lane], q1 = Qp[64+lane];
    float acc0 = 0.f, acc1 = 0.f;
    for (int j = jb; j < je; ++j) {
      const int s   = __builtin_amdgcn_readfirstlane(src_perm[j]);
      const int eid = __builtin_amdgcn_readfirstlane(eid_perm[j]);
      const float4* ef4 = (const float4*)(ef + (size_t)eid*16);
      float4 f0 = ef4[0], f1 = ef4[1], f2 = ef4[2], f3 = ef4[3];
      float fv[16];
      fv[0]=f0.x; fv[1]=f0.y; fv[2]=f0.z; fv[3]=f0.w;
      fv[4]=f1.x; fv[5]=f1.y; fv[6]=f1.z; fv[7]=f1.w;
      fv[8]=f2.x; fv[9]=f2.y; fv[10]=f2.z; fv[11]=f2.w;
      fv[12]=f3.x; fv[13]=f3.y; fv[14]=f3.z; fv[15]=f3.w;
      float r0 = b1c0, r1 = b1c1;
      #pragma unroll
      for (int k = 0; k < 16; ++k) { r0 = fmaf(fv[k], wr0[k], r0); r1 = fmaf(fv[k], wr1[k], r1); }
      const float* Pp = PQ + (size_t)s*256;
      acc0 += fmaxf(r0 + Pp[lane]    + q0, 0.f);
      acc1 += fmaxf(r1 + Pp[64+lane] + q1, 0.f);
    }
    float* Sp = S + (size_t)n*128;
    Sp[lane]      = acc0;
    Sp[64 + lane] = acc1;
  }
}

// ===== update2: h = LN(h + relu(h@U_a + inv*(S@V) + inv*cnt*w + ub))
__global__ __launch_bounds__(256) void k_update2(
    float* __restrict__ h, const float* __restrict__ S,
    const float* __restrict__ cnt, const float* __restrict__ U,
    const float* __restrict__ Vl, const float* __restrict__ wv,
    const float* __restrict__ ub, const float* __restrict__ lg,
    const float* __restrict__ lb)
{
  __shared__ float lds[1024];   // hs[4][128] | as[4][128]
  __shared__ float bst[4096];   // bounce, then partials ps[4][128]
  __shared__ float red[16];
  const int t = threadIdx.x, col = t & 127, hb = t >> 7;
  float br[128];
  // hb=0: columns of U_a (rows 0..127 of U); hb=1: columns of V
  const float4* U4 = (const float4*)U;
  #pragma unroll
  for (int c = 0; c < 4; ++c) {
    #pragma unroll
    for (int v = 0; v < 4; ++v) ((float4*)bst)[t + v*256] = U4[c*1024 + t + v*256];
    __syncthreads();
    if (hb == 0) {
      #pragma unroll
      for (int k = 0; k < 32; ++k) br[c*32 + k] = bst[k*128 + col];
    }
    __syncthreads();
  }
  const float4* V4 = (const float4*)Vl;
  #pragma unroll
  for (int c = 0; c < 4; ++c) {
    #pragma unroll
    for (int v = 0; v < 4; ++v) ((float4*)bst)[t + v*256] = V4[c*1024 + t + v*256];
    __syncthreads();
    if (hb == 1) {
      #pragma unroll
      for (int k = 0; k < 32; ++k) br[c*32 + k] = bst[k*128 + col];
    }
    __syncthreads();
  }
  const float ubc = ub[col], lgc = lg[col], lbc = lb[col], wc = wv[col];
  float* hs = lds; float* as = lds + 512; float* ps = bst;
  for (int n0 = blockIdx.x*4; n0 < NN; n0 += gridDim.x*4) {
    if (hb == 0) {
      ((float4*)hs)[t] = ((const float4*)h)[(size_t)n0*32 + t];
    } else {
      const int tt = t & 127;
      ((float4*)as)[tt] = ((const float4*)S)[(size_t)n0*32 + tt];
    }
    __syncthreads();
    const float4* A4 = (const float4*)(hb ? as : hs);
    float ac[4] = {0.f,0.f,0.f,0.f};
    #pragma unroll
    for (int kq = 0; kq < 32; ++kq) {
      const float b0 = br[4*kq], b1_ = br[4*kq+1], b2_ = br[4*kq+2], b3_ = br[4*kq+3];
      #pragma unroll
      for (int j = 0; j < 4; ++j) {
        float4 a = A4[j*32 + kq];
        ac[j] = fmaf(a.x,b0, fmaf(a.y,b1_, fmaf(a.z,b2_, fmaf(a.w,b3_, ac[j]))));
      }
    }
    if (hb == 1) {
      #pragma unroll
      for (int j = 0; j < 4; ++j) ps[j*128 + col] = ac[j];
    }
    __syncthreads();
    float rs[4], s1[4], s2[4];
    #pragma unroll
    for (int j = 0; j < 4; ++j) {
      const float cj = cnt[n0 + j];
      const float invj = 1.f / (cj + 1e-8f);
      float tot = ac[j] + invj*(ps[j*128 + col] + cj*wc) + ubc;  // junk for hb==1
      rs[j] = hs[j*128 + col] + fmaxf(tot, 0.f);
      s1[j] = rs[j]; s2[j] = rs[j]*rs[j];
    }
    #pragma unroll
    for (int o = 32; o > 0; o >>= 1) {
      #pragma unroll
      for (int j = 0; j < 4; ++j) {
        s1[j] += __shfl_xor(s1[j], o, 64);
        s2[j] += __shfl_xor(s2[j], o, 64);
      }
    }
    const int w = (t >> 6) & 1;
    if (t < 128 && (t & 63) == 0) {
      #pragma unroll
      for (int j = 0; j < 4; ++j) { red[(j*2+w)*2] = s1[j]; red[(j*2+w)*2+1] = s2[j]; }
    }
    __syncthreads();
    if (t < 128) {
      #pragma unroll
      for (int j = 0; j < 4; ++j) {
        const float sum1 = red[j*4] + red[j*4+2], sum2 = red[j*4+1] + red[j*4+3];
        const float mu = sum1 * (1.f/128.f);
        const float var = sum2 * (1.f/128.f) - mu*mu;
        h[(size_t)(n0+j)*128 + col] = (rs[j]-mu)*rsqrtf(var+1e-5f)*lgc + lbc;
      }
    }
    __syncthreads();
  }
}

// ===== attention scores: sco[n] = tanh(h@aw1+ab1)@aw2 + ab2
__global__ __launch_bounds__(256) void k_score(
    const float* __restrict__ h, const float* __restrict__ aw1,
    const float* __restrict__ ab1, const float* __restrict__ aw2,
    const float* __restrict__ ab2, float* __restrict__ sco)
{
  __shared__ float lds[4096];
  const int t = threadIdx.x, lane = t & 63, wid = t >> 6;
  float br[128];
  const float4* B4 = (const float4*)aw1;   // [128,64]
  #pragma unroll
  for (int c = 0; c < 2; ++c) {
    #pragma unroll
    for (int v = 0; v < 4; ++v) ((float4*)lds)[t + v*256] = B4[c*1024 + t + v*256];
    __syncthreads();
    #pragma unroll
    for (int k = 0; k < 64; ++k) br[c*64+k] = lds[k*64 + lane];
    __syncthreads();
  }
  const float b1c = ab1[lane], w2c = aw2[lane], b2c = ab2[0];
  float4* hs4 = (float4*)lds;
  for (int n0 = blockIdx.x*4; n0 < NN; n0 += gridDim.x*4) {
    if (t < 128) hs4[t] = ((const float4*)h)[(size_t)n0*32 + t];
    __syncthreads();
    float p0=0.f, p1=0.f, p2=0.f, p3=0.f;
    #pragma unroll
    for (int kq = 0; kq < 32; ++kq) {
      float4 a = hs4[wid*32 + kq];
      p0 = fmaf(a.x, br[4*kq],   p0);
      p1 = fmaf(a.y, br[4*kq+1], p1);
      p2 = fmaf(a.z, br[4*kq+2], p2);
      p3 = fmaf(a.w, br[4*kq+3], p3);
    }
    float t1 = tanhf(p0+p1+p2+p3 + b1c) * w2c;
    #pragma unroll
    for (int o = 32; o > 0; o >>= 1) t1 += __shfl_xor(t1, o, 64);
    if (lane == 0) sco[n0 + wid] = t1 + b2c;
    __syncthreads();
  }
}

__global__ __launch_bounds__(256) void k_rmax1(const float* __restrict__ sco,
                                               float* __restrict__ pmax)
{
  __shared__ float red[4];
  float m = -1e30f;
  for (int i = blockIdx.x*256 + threadIdx.x; i < NN; i += gridDim.x*256)
    m = fmaxf(m, sco[i]);
  #pragma unroll
  for (int o = 32; o > 0; o >>= 1) m = fmaxf(m, __shfl_xor(m, o, 64));
  if ((threadIdx.x & 63) == 0) red[threadIdx.x >> 6] = m;
  __syncthreads();
  if (threadIdx.x == 0)
    pmax[blockIdx.x] = fmaxf(fmaxf(red[0],red[1]), fmaxf(red[2],red[3]));
}

__global__ __launch_bounds__(256) void k_rmax2(const float* __restrict__ pmax,
                                               float* __restrict__ aux)
{
  __shared__ float red[4];
  float m = pmax[threadIdx.x];
  #pragma unroll
  for (int o = 32; o > 0; o >>= 1) m = fmaxf(m, __shfl_xor(m, o, 64));
  if ((threadIdx.x & 63) == 0) red[threadIdx.x >> 6] = m;
  __syncthreads();
  if (threadIdx.x == 0) {
    aux[0] = fmaxf(fmaxf(red[0],red[1]), fmaxf(red[2],red[3]));
    aux[1] = 0.f;
  }
  if (threadIdx.x < 128) aux[2 + threadIdx.x] = 0.f;
}

// ===== pool: gvec = sum_n exp(s_n - max) * h_n ; sumexp
__global__ __launch_bounds__(256) void k_pool(
    const float* __restrict__ h, const float* __restrict__ sco,
    float* __restrict__ aux)
{
  __shared__ float ps[256];
  __shared__ float wsum[2];
  const int t = threadIdx.x, col = t & 127, g = t >> 7;
  const float gmax = aux[0];
  float acc = 0.f, wacc = 0.f;
  for (int n0 = blockIdx.x*2; n0 < NN; n0 += gridDim.x*2) {
    const int n = n0 + g;
    const float w = expf(sco[n] - gmax);
    acc = fmaf(w, h[(size_t)n*128 + col], acc);
    if (col == 0) wacc += w;
  }
  ps[t] = acc;
  if (col == 0) wsum[g] = wacc;
  __syncthreads();
  if (t < 128) atomicAdd(&aux[2 + t], ps[t] + ps[128 + t]);
  if (t == 0)  atomicAdd(&aux[1], wsum[0] + wsum[1]);
}

// ===== head: out = relu(g@hw1+hb1)@hw2 + hb2
__global__ __launch_bounds__(256) void k_head(
    const float* __restrict__ aux, const float* __restrict__ hw1,
    const float* __restrict__ hb1, const float* __restrict__ hw2,
    const float* __restrict__ hb2, float* __restrict__ out)
{
  __shared__ float gs[128], hsm[128];
  const int t = threadIdx.x;
  if (t < 128) gs[t] = aux[2+t] / aux[1];
  __syncthreads();
  if (t < 128) {
    float a = hb1[t];
    #pragma unroll 4
    for (int k = 0; k < 128; ++k) a = fmaf(gs[k], hw1[k*128 + t], a);
    hsm[t] = fmaxf(a, 0.f);
  }
  __syncthreads();
  if (t < 32) {
    float a = hb2[t];
    #pragma unroll 4
    for (int k = 0; k < 128; ++k) a = fmaf(hsm[k], hw2[k*32 + t], a);
    out[t] = a;
  }
}

extern "C" void kernel_launch(void* const* d_in, const int* in_sizes, int n_in,
                              void* d_out, int out_size, void* d_ws, size_t ws_size,
                              hipStream_t stream)
{
  const float* nf   = (const float*)d_in[0];
  const void*  eraw = d_in[1];               // int32 or int64, detected on device
  const float* ef   = (const float*)d_in[2];
  const float* ew1  = (const float*)d_in[3];
  const float* eb1  = (const float*)d_in[4];
  const float* elng = (const float*)d_in[5];
  const float* elnb = (const float*)d_in[6];
  const float* ew2  = (const float*)d_in[7];
  const float* eb2  = (const float*)d_in[8];
  const float* mw1  = (const float*)d_in[9];
  const float* mb1  = (const float*)d_in[10];
  const float* mw2  = (const float*)d_in[11];
  const float* mb2  = (const float*)d_in[12];
  const float* uw   = (const float*)d_in[13];
  const float* ubb  = (const float*)d_in[14];
  const float* lng  = (const float*)d_in[15];
  const float* lnb  = (const float*)d_in[16];
  const float* aw1  = (const float*)d_in[17];
  const float* ab1  = (const float*)d_in[18];
  const float* aw2  = (const float*)d_in[19];
  const float* ab2  = (const float*)d_in[20];
  const float* hw1  = (const float*)d_in[21];
  const float* hb1  = (const float*)d_in[22];
  const float* hw2  = (const float*)d_in[23];
  const float* hb2  = (const float*)d_in[24];

  float* ws   = (float*)d_ws;
  float* h    = ws;
  float* PQ   = ws + (size_t)NN*HH;
  float* S    = ws + (size_t)NN*HH*3;
  float* cnt  = ws + (size_t)NN*HH*4;
  float* sco  = cnt + NN;
  float* pmax = sco + NN;
  float* aux  = pmax + 256;
  int*   flag   = (int*)(aux + 130);
  int*   rowoff = flag + 2;                  // [NN+1]
  int*   cursor = rowoff + NN + 1;           // [NN]
  int*   srcp   = cursor + NN;               // [EE]
  int*   eidp   = srcp + EE;                 // [EE]
  int*   bsum   = eidp + EE;                 // [SNB]
  float* V  = (float*)(((uintptr_t)(bsum + SNB) + 15) & ~(uintptr_t)15); // [L][128][128]
  float* wv = V + (size_t)LLAYERS*HH*HH;     // [L][128]

  hipMemsetAsync(cnt, 0, NN*sizeof(float), stream);
  k_detect<<<1, 64, 0, stream>>>((const unsigned int*)eraw, flag);
  k_cnt<<<1024, 256, 0, stream>>>(eraw, flag, cnt);
  k_scan_a<<<SNB, 256, 0, stream>>>(cnt, bsum);
  k_scan_b<<<1, 256, 0, stream>>>(bsum);
  k_scan_c<<<SNB, 256, 0, stream>>>(cnt, bsum, rowoff, cursor);
  k_scatter<<<1024, 256, 0, stream>>>(eraw, flag, cursor, srcp, eidp);
  k_prep<<<LLAYERS*8, 256, 0, stream>>>(mw2, mb2, uw, V, wv);
  k_enc<<<1024, 256, 0, stream>>>(nf, ew1, eb1, elng, elnb, ew2, eb2, h);

  for (int i = 0; i < LLAYERS; ++i) {
    k_pq<<<1024, 256, 0, stream>>>(h, mw1 + (size_t)i*272*128, PQ);
    k_edge_csr<<<2048, 256, 0, stream>>>(rowoff, srcp, eidp, ef, PQ,
                                         mw1 + ((size_t)i*272 + 256)*128,
                                         mb1 + (size_t)i*128, S);
    k_update2<<<1024, 256, 0, stream>>>(h, S, cnt,
                                        uw + (size_t)i*256*128,
                                        V  + (size_t)i*HH*HH,
                                        wv + (size_t)i*HH,
                                        ubb + (size_t)i*128,
                                        lng + (size_t)i*128,
                                        lnb + (size_t)i*128);
  }

  k_score<<<512, 256, 0, stream>>>(h, aw1, ab1, aw2, ab2, sco);
  k_rmax1<<<256, 256, 0, stream>>>(sco, pmax);
  k_rmax2<<<1, 256, 0, stream>>>(pmax, aux);
  k_pool<<<256, 256, 0, stream>>>(h, sco, aux);
  k_head<<<1, 256, 0, stream>>>(aux, hw1, hb1, hw2, hb2, (float*)d_out);
}

// Round 13
// 2273.500 us; speedup vs baseline: 1.2104x; 1.2104x over previous
//
#include <hip/hip_runtime.h>
#include <hip/hip_bf16.h>
#include <stdint.h>

#define NN 100000
#define EE 600000
#define FF 64
#define EDIM 16
#define HH 128
#define LLAYERS 4
#define OO 32

#define SCH 512                         // scan chunk per block
#define SNB ((NN + SCH - 1) / SCH)      // 196 scan blocks

// ---------------------------------------------------------------------------
// ws layout (floats):
//  h   : [0, N*H)            node state
//  PQ  : [N*H, N*3H)         P = h@W1a (cols 0..127), Q = h@W1b (cols 128..255)
//  S   : [N*3H, N*4H)        per-dst hidden sums (raw; k_tagg is fused away)
//  cnt : [N*4H, +N)          in-degree (float)
//  sco : +N ; pmax: +256 ; aux: +130
//  ints: flag(2), rowoff(N+1), cursor(N), src_perm(E), eid_perm(E), bsum(SNB)
//  V   : [L][128][128]       V = W2 @ U_b   (k_prep, once per call)
//  wv  : [L][128]            w = b2 @ U_b
//
// Fusion: update pre-act = h@U_a + (inv*S)@V + (cnt*inv)*w + ub.
// R11 lesson: do inv-scaling in the STAGING phase (as = inv*S, gj = cnt*inv
// in LDS), not per-thread in the combine loop — R11's combine-side divisions
// pushed VGPR 96->120 and VALU cycles ~2x (355us vs 219us).
// ---------------------------------------------------------------------------

// ===== detect edge_index dtype (int64 has all-zero high words)
__global__ __launch_bounds__(64) void k_detect(const unsigned int* __restrict__ w,
                                               int* __restrict__ flag)
{
  const int t = threadIdx.x;
  int z = (w[2*t + 1] == 0u) ? 1 : 0;
  #pragma unroll
  for (int o = 32; o > 0; o >>= 1) z &= __shfl_xor(z, o, 64);
  if (t == 0) *flag = z;
}

// ===== in-degree
__global__ __launch_bounds__(256) void k_cnt(const void* __restrict__ buf,
                                             const int* __restrict__ flag,
                                             float* __restrict__ cnt)
{
  const int is64 = *flag;
  const long long* b64 = (const long long*)buf;
  const int*       b32 = (const int*)buf;
  for (int e = blockIdx.x*256 + threadIdx.x; e < EE; e += gridDim.x*256) {
    const int d = is64 ? (int)b64[EE + e] : b32[EE + e];
    atomicAdd(&cnt[d], 1.0f);
  }
}

// ===== scan pass A: per-block degree sums (coalesced)
__global__ __launch_bounds__(256) void k_scan_a(const float* __restrict__ cnt,
                                                int* __restrict__ bsum)
{
  __shared__ int red[4];
  const int base = blockIdx.x * SCH;
  const int t = threadIdx.x;
  int s = 0;
  const int i0 = base + t, i1 = base + 256 + t;
  if (i0 < NN) s += (int)cnt[i0];
  if (i1 < NN) s += (int)cnt[i1];
  #pragma unroll
  for (int o = 32; o > 0; o >>= 1) s += __shfl_xor(s, o, 64);
  if ((t & 63) == 0) red[t >> 6] = s;
  __syncthreads();
  if (t == 0) bsum[blockIdx.x] = red[0] + red[1] + red[2] + red[3];
}

// ===== scan pass B: exclusive scan of SNB block sums (1 block)
__global__ __launch_bounds__(256) void k_scan_b(int* __restrict__ bsum)
{
  __shared__ int ps[256];
  const int t = threadIdx.x;
  const int v = (t < SNB) ? bsum[t] : 0;
  ps[t] = v;
  __syncthreads();
  for (int off = 1; off < 256; off <<= 1) {
    int u = (t >= off) ? ps[t - off] : 0;
    __syncthreads();
    ps[t] += u;
    __syncthreads();
  }
  if (t < SNB) bsum[t] = ps[t] - v;   // exclusive block offsets
}

// ===== scan pass C: local exclusive scan + block offset -> rowoff, cursor
__global__ __launch_bounds__(256) void k_scan_c(const float* __restrict__ cnt,
                                                const int* __restrict__ bsum,
                                                int* __restrict__ rowoff,
                                                int* __restrict__ cursor)
{
  __shared__ int vals[SCH];
  __shared__ int ps[256];
  const int base = blockIdx.x * SCH;
  const int t = threadIdx.x;
  const int i0 = base + t, i1 = base + 256 + t;
  vals[t]       = (i0 < NN) ? (int)cnt[i0] : 0;
  vals[256 + t] = (i1 < NN) ? (int)cnt[i1] : 0;
  __syncthreads();
  const int a = vals[2*t], b = vals[2*t + 1];
  const int pair = a + b;
  ps[t] = pair;
  __syncthreads();
  for (int off = 1; off < 256; off <<= 1) {
    int u = (t >= off) ? ps[t - off] : 0;
    __syncthreads();
    ps[t] += u;
    __syncthreads();
  }
  const int excl = bsum[blockIdx.x] + ps[t] - pair;
  const int j0 = base + 2*t, j1 = j0 + 1;
  if (j0 < NN) { rowoff[j0] = excl;     cursor[j0] = excl; }
  if (j1 < NN) { rowoff[j1] = excl + a; cursor[j1] = excl + a; }
  if (j1 == NN - 1) rowoff[NN] = excl + pair;   // NN even -> last elem is a j1
}

// ===== bucket edges by dst
__global__ __launch_bounds__(256) void k_scatter(const void* __restrict__ buf,
                                                 const int* __restrict__ flag,
                                                 int* __restrict__ cursor,
                                                 int* __restrict__ src_perm,
                                                 int* __restrict__ eid_perm)
{
  const int is64 = *flag;
  const long long* b64 = (const long long*)buf;
  const int*       b32 = (const int*)buf;
  for (int e = blockIdx.x*256 + threadIdx.x; e < EE; e += gridDim.x*256) {
    const int s = is64 ? (int)b64[e]      : b32[e];
    const int d = is64 ? (int)b64[EE + e] : b32[EE + e];
    const int pos = atomicAdd(&cursor[d], 1);
    src_perm[pos] = s;
    eid_perm[pos] = e;
  }
}

// ===== prep: V[i] = W2[i] @ Ub[i], wv[i] = b2[i] @ Ub[i]  (Ub = U rows 128..255)
// grid = LLAYERS*8; block handles 16 rows of V for one layer.
__global__ __launch_bounds__(256) void k_prep(
    const float* __restrict__ mw2, const float* __restrict__ mb2,
    const float* __restrict__ uw, float* __restrict__ V,
    float* __restrict__ wv)
{
  __shared__ float w2s[16*128];
  const int L = blockIdx.x >> 3, sub = blockIdx.x & 7;
  const int t = threadIdx.x, col = t & 127, half = t >> 7;
  const float* W2 = mw2 + (size_t)L*128*128;
  const float* Ub = uw  + (size_t)L*256*128 + 128*128;
  const float* b2 = mb2 + (size_t)L*128;
  float* Vl = V  + (size_t)L*128*128;
  float* wl = wv + (size_t)L*128;
  // stage W2 rows [sub*16, sub*16+16) : 512 float4
  const float4* W24 = (const float4*)W2;
  ((float4*)w2s)[t]       = W24[sub*512 + t];
  ((float4*)w2s)[256 + t] = W24[sub*512 + 256 + t];
  // column col of Ub in registers
  float ur[128];
  #pragma unroll 8
  for (int k = 0; k < 128; ++k) ur[k] = Ub[k*128 + col];
  __syncthreads();
  #pragma unroll
  for (int i = 0; i < 8; ++i) {
    const int r = half*8 + i;
    float acc = 0.f;
    #pragma unroll 8
    for (int k = 0; k < 128; ++k) acc = fmaf(w2s[r*128 + k], ur[k], acc);
    Vl[(size_t)(sub*16 + r)*128 + col] = acc;
  }
  if (sub == 0 && half == 0) {
    float acc = 0.f;
    #pragma unroll 8
    for (int k = 0; k < 128; ++k) acc = fmaf(b2[k], ur[k], acc);
    wl[col] = acc;
  }
}

// ===== encoder: h = relu(LN(relu(x@w1+b1))@w2+b2), fused, 2 nodes/block-iter
__global__ __launch_bounds__(256) void k_enc(
    const float* __restrict__ nf, const float* __restrict__ w1,
    const float* __restrict__ b1, const float* __restrict__ lng,
    const float* __restrict__ lnb, const float* __restrict__ w2,
    const float* __restrict__ b2, float* __restrict__ h)
{
  __shared__ float lds[4096];
  __shared__ float red[8];
  const int t = threadIdx.x;
  const int col = t & 127, g = t >> 7;
  float br1[64], br2[128];
  const float4* w14 = (const float4*)w1;
  #pragma unroll
  for (int c = 0; c < 2; ++c) {
    #pragma unroll
    for (int v = 0; v < 4; ++v) ((float4*)lds)[t + v*256] = w14[c*1024 + t + v*256];
    __syncthreads();
    #pragma unroll
    for (int k = 0; k < 32; ++k) br1[c*32+k] = lds[k*128 + col];
    __syncthreads();
  }
  const float4* w24 = (const float4*)w2;
  #pragma unroll
  for (int c = 0; c < 4; ++c) {
    #pragma unroll
    for (int v = 0; v < 4; ++v) ((float4*)lds)[t + v*256] = w24[c*1024 + t + v*256];
    __syncthreads();
    #pragma unroll
    for (int k = 0; k < 32; ++k) br2[c*32+k] = lds[k*128 + col];
    __syncthreads();
  }
  const float b1c = b1[col], gc = lng[col], bc = lnb[col], b2c = b2[col];
  float* xs = lds;          // xs[2][64]
  float* ys = lds + 128;    // ys[2][128]
  for (int n0 = blockIdx.x * 2; n0 < NN; n0 += gridDim.x * 2) {
    const int node = n0 + g;
    if (col < 16) ((float4*)xs)[g*16 + col] = ((const float4*)nf)[(size_t)node*16 + col];
    __syncthreads();
    float a = b1c;
    #pragma unroll
    for (int k = 0; k < 64; ++k) a = fmaf(xs[g*64+k], br1[k], a);
    float v = fmaxf(a, 0.f);
    float s1 = v, s2 = v*v;
    #pragma unroll
    for (int o = 32; o > 0; o >>= 1) { s1 += __shfl_xor(s1, o, 64); s2 += __shfl_xor(s2, o, 64); }
    const int w = (t >> 6) & 1;
    if ((t & 63) == 0) { red[(g*2+w)*2] = s1; red[(g*2+w)*2+1] = s2; }
    __syncthreads();
    const float sum1 = red[g*4] + red[g*4+2], sum2 = red[g*4+1] + red[g*4+3];
    const float mu = sum1 * (1.f/128.f);
    const float var = sum2 * (1.f/128.f) - mu*mu;
    const float y = (v - mu) * rsqrtf(var + 1e-5f) * gc + bc;
    ys[g*128+col] = y;
    __syncthreads();
    float a2 = b2c;
    #pragma unroll
    for (int k = 0; k < 128; ++k) a2 = fmaf(ys[g*128+k], br2[k], a2);
    h[(size_t)node*128 + col] = fmaxf(a2, 0.f);
    __syncthreads();
  }
}

// ===== PQ = h @ [W1a | W1b]  (N x 256), 4 nodes/block-iter
__global__ __launch_bounds__(256) void k_pq(
    const float* __restrict__ h, const float* __restrict__ W1,
    float* __restrict__ PQ)
{
  __shared__ float lds[4096];
  const int t = threadIdx.x;
  const int col = t & 127, hb = t >> 7;
  float br[128];
  const float4* B4 = (const float4*)W1;
  #pragma unroll
  for (int c = 0; c < 8; ++c) {
    #pragma unroll
    for (int v = 0; v < 4; ++v) ((float4*)lds)[t + v*256] = B4[c*1024 + t + v*256];
    __syncthreads();
    if ((c >> 2) == hb) {
      #pragma unroll
      for (int k = 0; k < 32; ++k) br[(c&3)*32 + k] = lds[k*128 + col];
    }
    __syncthreads();
  }
  float4* hs4 = (float4*)lds;
  for (int n0 = blockIdx.x*4; n0 < NN; n0 += gridDim.x*4) {
    if (t < 128) hs4[t] = ((const float4*)h)[(size_t)n0*32 + t];
    __syncthreads();
    float ac[4] = {0.f,0.f,0.f,0.f};
    #pragma unroll
    for (int kq = 0; kq < 32; ++kq) {
      const float b0 = br[4*kq], b1_ = br[4*kq+1], b2_ = br[4*kq+2], b3_ = br[4*kq+3];
      #pragma unroll
      for (int j = 0; j < 4; ++j) {
        float4 a = hs4[j*32 + kq];
        ac[j] = fmaf(a.x,b0, fmaf(a.y,b1_, fmaf(a.z,b2_, fmaf(a.w,b3_, ac[j]))));
      }
    }
    #pragma unroll
    for (int j = 0; j < 4; ++j) PQ[(size_t)(n0+j)*256 + t] = ac[j];
    __syncthreads();
  }
}

// ===== edge (CSR): per dst node, acc += relu(P[src]+Q[dst]+ef@W1c+b1); S once
__global__ __launch_bounds__(256) void k_edge_csr(
    const int* __restrict__ rowoff, const int* __restrict__ src_perm,
    const int* __restrict__ eid_perm, const float* __restrict__ ef,
    const float* __restrict__ PQ, const float* __restrict__ W1c,
    const float* __restrict__ b1, float* __restrict__ S)
{
  const int t = threadIdx.x;
  const int lane = t & 63, wid = t >> 6;
  float wr0[16], wr1[16];
  #pragma unroll
  for (int k = 0; k < 16; ++k) {
    wr0[k] = W1c[k*128 + lane];
    wr1[k] = W1c[k*128 + 64 + lane];
  }
  const float b1c0 = b1[lane], b1c1 = b1[64+lane];
  const int nwaves = gridDim.x * 4;
  for (int n = blockIdx.x*4 + wid; n < NN; n += nwaves) {
    const int jb = rowoff[n], je = rowoff[n+1];
    const float* Qp = PQ + (size_t)n*256 + 128;
    const float q0 = Qp[lane], q1 = Qp[64+lane];
    float acc0 = 0.f, acc1 = 0.f;
    for (int j = jb; j < je; ++j) {
      const int s   = __builtin_amdgcn_readfirstlane(src_perm[j]);
      const int eid = __builtin_amdgcn_readfirstlane(eid_perm[j]);
      const float4* ef4 = (const float4*)(ef + (size_t)eid*16);
      float4 f0 = ef4[0], f1 = ef4[1], f2 = ef4[2], f3 = ef4[3];
      float fv[16];
      fv[0]=f0.x; fv[1]=f0.y; fv[2]=f0.z; fv[3]=f0.w;
      fv[4]=f1.x; fv[5]=f1.y; fv[6]=f1.z; fv[7]=f1.w;
      fv[8]=f2.x; fv[9]=f2.y; fv[10]=f2.z; fv[11]=f2.w;
      fv[12]=f3.x; fv[13]=f3.y; fv[14]=f3.z; fv[15]=f3.w;
      float r0 = b1c0, r1 = b1c1;
      #pragma unroll
      for (int k = 0; k < 16; ++k) { r0 = fmaf(fv[k], wr0[k], r0); r1 = fmaf(fv[k], wr1[k], r1); }
      const float* Pp = PQ + (size_t)s*256;
      acc0 += fmaxf(r0 + Pp[lane]    + q0, 0.f);
      acc1 += fmaxf(r1 + Pp[64+lane] + q1, 0.f);
    }
    float* Sp = S + (size_t)n*128;
    Sp[lane]      = acc0;
    Sp[64 + lane] = acc1;
  }
}

// ===== update2: h = LN(h + relu(h@U_a + (inv*S)@V + (cnt*inv)*w + ub))
// Staging computes as = inv*S and gj = cnt*inv (R10 k_update codegen shape).
__global__ __launch_bounds__(256) void k_update2(
    float* __restrict__ h, const float* __restrict__ S,
    const float* __restrict__ cnt, const float* __restrict__ U,
    const float* __restrict__ Vl, const float* __restrict__ wv,
    const float* __restrict__ ub, const float* __restrict__ lg,
    const float* __restrict__ lb)
{
  __shared__ float lds[1024];   // hs[4][128] | as[4][128]
  __shared__ float bst[4096];   // bounce, then partials ps[4][128]
  __shared__ float red[16];
  __shared__ float gj[4];
  const int t = threadIdx.x, col = t & 127, hb = t >> 7;
  float br[128];
  // hb=0: columns of U_a (rows 0..127 of U); hb=1: columns of V
  const float4* U4 = (const float4*)U;
  #pragma unroll
  for (int c = 0; c < 4; ++c) {
    #pragma unroll
    for (int v = 0; v < 4; ++v) ((float4*)bst)[t + v*256] = U4[c*1024 + t + v*256];
    __syncthreads();
    if (hb == 0) {
      #pragma unroll
      for (int k = 0; k < 32; ++k) br[c*32 + k] = bst[k*128 + col];
    }
    __syncthreads();
  }
  const float4* V4 = (const float4*)Vl;
  #pragma unroll
  for (int c = 0; c < 4; ++c) {
    #pragma unroll
    for (int v = 0; v < 4; ++v) ((float4*)bst)[t + v*256] = V4[c*1024 + t + v*256];
    __syncthreads();
    if (hb == 1) {
      #pragma unroll
      for (int k = 0; k < 32; ++k) br[c*32 + k] = bst[k*128 + col];
    }
    __syncthreads();
  }
  const float ubc = ub[col], lgc = lg[col], lbc = lb[col], wc = wv[col];
  float* hs = lds; float* as = lds + 512; float* ps = bst;
  for (int n0 = blockIdx.x*4; n0 < NN; n0 += gridDim.x*4) {
    if (hb == 0) {
      ((float4*)hs)[t] = ((const float4*)h)[(size_t)n0*32 + t];
    } else {
      const int tt = t & 127;
      const int j = tt >> 5, k4 = tt & 31;
      const float c_ = cnt[n0 + j];
      const float inv = 1.f / (c_ + 1e-8f);
      float4 sv = ((const float4*)S)[(size_t)n0*32 + tt];
      float4 av;
      av.x = sv.x*inv; av.y = sv.y*inv; av.z = sv.z*inv; av.w = sv.w*inv;
      ((float4*)as)[tt] = av;
      if (k4 == 0) gj[j] = c_ * inv;
    }
    __syncthreads();
    const float4* A4 = (const float4*)(hb ? as : hs);
    float ac[4] = {0.f,0.f,0.f,0.f};
    #pragma unroll
    for (int kq = 0; kq < 32; ++kq) {
      const float b0 = br[4*kq], b1_ = br[4*kq+1], b2_ = br[4*kq+2], b3_ = br[4*kq+3];
      #pragma unroll
      for (int j = 0; j < 4; ++j) {
        float4 a = A4[j*32 + kq];
        ac[j] = fmaf(a.x,b0, fmaf(a.y,b1_, fmaf(a.z,b2_, fmaf(a.w,b3_, ac[j]))));
      }
    }
    if (hb == 1) {
      #pragma unroll
      for (int j = 0; j < 4; ++j) ps[j*128 + col] = ac[j];
    }
    __syncthreads();
    float rs[4], s1[4], s2[4];
    #pragma unroll
    for (int j = 0; j < 4; ++j) {
      float tot = ac[j] + ps[j*128 + col] + gj[j]*wc + ubc;  // junk for hb==1
      rs[j] = hs[j*128 + col] + fmaxf(tot, 0.f);
      s1[j] = rs[j]; s2[j] = rs[j]*rs[j];
    }
    #pragma unroll
    for (int o = 32; o > 0; o >>= 1) {
      #pragma unroll
      for (int j = 0; j < 4; ++j) {
        s1[j] += __shfl_xor(s1[j], o, 64);
        s2[j] += __shfl_xor(s2[j], o, 64);
      }
    }
    const int w = (t >> 6) & 1;
    if (t < 128 && (t & 63) == 0) {
      #pragma unroll
      for (int j = 0; j < 4; ++j) { red[(j*2+w)*2] = s1[j]; red[(j*2+w)*2+1] = s2[j]; }
    }
    __syncthreads();
    if (t < 128) {
      #pragma unroll
      for (int j = 0; j < 4; ++j) {
        const float sum1 = red[j*4] + red[j*4+2], sum2 = red[j*4+1] + red[j*4+3];
        const float mu = sum1 * (1.f/128.f);
        const float var = sum2 * (1.f/128.f) - mu*mu;
        h[(size_t)(n0+j)*128 + col] = (rs[j]-mu)*rsqrtf(var+1e-5f)*lgc + lbc;
      }
    }
    __syncthreads();
  }
}

// ===== attention scores: sco[n] = tanh(h@aw1+ab1)@aw2 + ab2
__global__ __launch_bounds__(256) void k_score(
    const float* __restrict__ h, const float* __restrict__ aw1,
    const float* __restrict__ ab1, const float* __restrict__ aw2,
    const float* __restrict__ ab2, float* __restrict__ sco)
{
  __shared__ float lds[4096];
  const int t = threadIdx.x, lane = t & 63, wid = t >> 6;
  float br[128];
  const float4* B4 = (const float4*)aw1;   // [128,64]
  #pragma unroll
  for (int c = 0; c < 2; ++c) {
    #pragma unroll
    for (int v = 0; v < 4; ++v) ((float4*)lds)[t + v*256] = B4[c*1024 + t + v*256];
    __syncthreads();
    #pragma unroll
    for (int k = 0; k < 64; ++k) br[c*64+k] = lds[k*64 + lane];
    __syncthreads();
  }
  const float b1c = ab1[lane], w2c = aw2[lane], b2c = ab2[0];
  float4* hs4 = (float4*)lds;
  for (int n0 = blockIdx.x*4; n0 < NN; n0 += gridDim.x*4) {
    if (t < 128) hs4[t] = ((const float4*)h)[(size_t)n0*32 + t];
    __syncthreads();
    float p0=0.f, p1=0.f, p2=0.f, p3=0.f;
    #pragma unroll
    for (int kq = 0; kq < 32; ++kq) {
      float4 a = hs4[wid*32 + kq];
      p0 = fmaf(a.x, br[4*kq],   p0);
      p1 = fmaf(a.y, br[4*kq+1], p1);
      p2 = fmaf(a.z, br[4*kq+2], p2);
      p3 = fmaf(a.w, br[4*kq+3], p3);
    }
    float t1 = tanhf(p0+p1+p2+p3 + b1c) * w2c;
    #pragma unroll
    for (int o = 32; o > 0; o >>= 1) t1 += __shfl_xor(t1, o, 64);
    if (lane == 0) sco[n0 + wid] = t1 + b2c;
    __syncthreads();
  }
}

__global__ __launch_bounds__(256) void k_rmax1(const float* __restrict__ sco,
                                               float* __restrict__ pmax)
{
  __shared__ float red[4];
  float m = -1e30f;
  for (int i = blockIdx.x*256 + threadIdx.x; i < NN; i += gridDim.x*256)
    m = fmaxf(m, sco[i]);
  #pragma unroll
  for (int o = 32; o > 0; o >>= 1) m = fmaxf(m, __shfl_xor(m, o, 64));
  if ((threadIdx.x & 63) == 0) red[threadIdx.x >> 6] = m;
  __syncthreads();
  if (threadIdx.x == 0)
    pmax[blockIdx.x] = fmaxf(fmaxf(red[0],red[1]), fmaxf(red[2],red[3]));
}

__global__ __launch_bounds__(256) void k_rmax2(const float* __restrict__ pmax,
                                               float* __restrict__ aux)
{
  __shared__ float red[4];
  float m = pmax[threadIdx.x];
  #pragma unroll
  for (int o = 32; o > 0; o >>= 1) m = fmaxf(m, __shfl_xor(m, o, 64));
  if ((threadIdx.x & 63) == 0) red[threadIdx.x >> 6] = m;
  __syncthreads();
  if (threadIdx.x == 0) {
    aux[0] = fmaxf(fmaxf(red[0],red[1]), fmaxf(red[2],red[3]));
    aux[1] = 0.f;
  }
  if (threadIdx.x < 128) aux[2 + threadIdx.x] = 0.f;
}

// ===== pool: gvec = sum_n exp(s_n - max) * h_n ; sumexp
__global__ __launch_bounds__(256) void k_pool(
    const float* __restrict__ h, const float* __restrict__ sco,
    float* __restrict__ aux)
{
  __shared__ float ps[256];
  __shared__ float wsum[2];
  const int t = threadIdx.x, col = t & 127, g = t >> 7;
  const float gmax = aux[0];
  float acc = 0.f, wacc = 0.f;
  for (int n0 = blockIdx.x*2; n0 < NN; n0 += gridDim.x*2) {
    const int n = n0 + g;
    const float w = expf(sco[n] - gmax);
    acc = fmaf(w, h[(size_t)n*128 + col], acc);
    if (col == 0) wacc += w;
  }
  ps[t] = acc;
  if (col == 0) wsum[g] = wacc;
  __syncthreads();
  if (t < 128) atomicAdd(&aux[2 + t], ps[t] + ps[128 + t]);
  if (t == 0)  atomicAdd(&aux[1], wsum[0] + wsum[1]);
}

// ===== head: out = relu(g@hw1+hb1)@hw2 + hb2
__global__ __launch_bounds__(256) void k_head(
    const float* __restrict__ aux, const float* __restrict__ hw1,
    const float* __restrict__ hb1, const float* __restrict__ hw2,
    const float* __restrict__ hb2, float* __restrict__ out)
{
  __shared__ float gs[128], hsm[128];
  const int t = threadIdx.x;
  if (t < 128) gs[t] = aux[2+t] / aux[1];
  __syncthreads();
  if (t < 128) {
    float a = hb1[t];
    #pragma unroll 4
    for (int k = 0; k < 128; ++k) a = fmaf(gs[k], hw1[k*128 + t], a);
    hsm[t] = fmaxf(a, 0.f);
  }
  __syncthreads();
  if (t < 32) {
    float a = hb2[t];
    #pragma unroll 4
    for (int k = 0; k < 128; ++k) a = fmaf(hsm[k], hw2[k*32 + t], a);
    out[t] = a;
  }
}

extern "C" void kernel_launch(void* const* d_in, const int* in_sizes, int n_in,
                              void* d_out, int out_size, void* d_ws, size_t ws_size,
                              hipStream_t stream)
{
  const float* nf   = (const float*)d_in[0];
  const void*  eraw = d_in[1];               // int32 or int64, detected on device
  const float* ef   = (const float*)d_in[2];
  const float* ew1  = (const float*)d_in[3];
  const float* eb1  = (const float*)d_in[4];
  const float* elng = (const float*)d_in[5];
  const float* elnb = (const float*)d_in[6];
  const float* ew2  = (const float*)d_in[7];
  const float* eb2  = (const float*)d_in[8];
  const float* mw1  = (const float*)d_in[9];
  const float* mb1  = (const float*)d_in[10];
  const float* mw2  = (const float*)d_in[11];
  const float* mb2  = (const float*)d_in[12];
  const float* uw   = (const float*)d_in[13];
  const float* ubb  = (const float*)d_in[14];
  const float* lng  = (const float*)d_in[15];
  const float* lnb  = (const float*)d_in[16];
  const float* aw1  = (const float*)d_in[17];
  const float* ab1  = (const float*)d_in[18];
  const float* aw2  = (const float*)d_in[19];
  const float* ab2  = (const float*)d_in[20];
  const float* hw1  = (const float*)d_in[21];
  const float* hb1  = (const float*)d_in[22];
  const float* hw2  = (const float*)d_in[23];
  const float* hb2  = (const float*)d_in[24];

  float* ws   = (float*)d_ws;
  float* h    = ws;
  float* PQ   = ws + (size_t)NN*HH;
  float* S    = ws + (size_t)NN*HH*3;
  float* cnt  = ws + (size_t)NN*HH*4;
  float* sco  = cnt + NN;
  float* pmax = sco + NN;
  float* aux  = pmax + 256;
  int*   flag   = (int*)(aux + 130);
  int*   rowoff = flag + 2;                  // [NN+1]
  int*   cursor = rowoff + NN + 1;           // [NN]
  int*   srcp   = cursor + NN;               // [EE]
  int*   eidp   = srcp + EE;                 // [EE]
  int*   bsum   = eidp + EE;                 // [SNB]
  float* V  = (float*)(((uintptr_t)(bsum + SNB) + 15) & ~(uintptr_t)15); // [L][128][128]
  float* wv = V + (size_t)LLAYERS*HH*HH;     // [L][128]

  hipMemsetAsync(cnt, 0, NN*sizeof(float), stream);
  k_detect<<<1, 64, 0, stream>>>((const unsigned int*)eraw, flag);
  k_cnt<<<1024, 256, 0, stream>>>(eraw, flag, cnt);
  k_scan_a<<<SNB, 256, 0, stream>>>(cnt, bsum);
  k_scan_b<<<1, 256, 0, stream>>>(bsum);
  k_scan_c<<<SNB, 256, 0, stream>>>(cnt, bsum, rowoff, cursor);
  k_scatter<<<1024, 256, 0, stream>>>(eraw, flag, cursor, srcp, eidp);
  k_prep<<<LLAYERS*8, 256, 0, stream>>>(mw2, mb2, uw, V, wv);
  k_enc<<<1024, 256, 0, stream>>>(nf, ew1, eb1, elng, elnb, ew2, eb2, h);

  for (int i = 0; i < LLAYERS; ++i) {
    k_pq<<<1024, 256, 0, stream>>>(h, mw1 + (size_t)i*272*128, PQ);
    k_edge_csr<<<2048, 256, 0, stream>>>(rowoff, srcp, eidp, ef, PQ,
                                         mw1 + ((size_t)i*272 + 256)*128,
                                         mb1 + (size_t)i*128, S);
    k_update2<<<1024, 256, 0, stream>>>(h, S, cnt,
                                        uw + (size_t)i*256*128,
                                        V  + (size_t)i*HH*HH,
                                        wv + (size_t)i*HH,
                                        ubb + (size_t)i*128,
                                        lng + (size_t)i*128,
                                        lnb + (size_t)i*128);
  }

  k_score<<<512, 256, 0, stream>>>(h, aw1, ab1, aw2, ab2, sco);
  k_rmax1<<<256, 256, 0, stream>>>(sco, pmax);
  k_rmax2<<<1, 256, 0, stream>>>(pmax, aux);
  k_pool<<<256, 256, 0, stream>>>(h, sco, aux);
  k_head<<<1, 256, 0, stream>>>(aux, hw1, hb1, hw2, hb2, (float*)d_out);
}